// Round 1
// baseline (131.475 us; speedup 1.0000x reference)
//
#include <hip/hip_runtime.h>

#define N 4096
#define BLK 256

// One block per row. Row i needs:
//   scores[i][j] = ana_scores[i*(i-1)/2 + j]  for j < i  (contiguous!)
//   scores[i][i] = eps_scores[i]
//   mask[i][0..i]
// bc[i]   = max over mask==1 of scores[i][j]          (global min is dead code:
//           every row has a mask=1 entry and min <= all scores)
// loss[i] = max(0, max_{j<=i} (1-mask)*pc * (1 + score - bc))
//           pc = false_new on diag, else d*lc0 + (1-d)*lc1 with d = mask[i][i]
__global__ __launch_bounds__(BLK) void mention_loss_kernel(
    const float* __restrict__ eps_scores,
    const float* __restrict__ ana_scores,
    const float* __restrict__ mask,
    const float* __restrict__ link_costs,
    const float* __restrict__ false_new_cost,
    float* __restrict__ out)
{
    // Longest rows first: blockIdx 0 -> row N-1.
    const int row = N - 1 - (int)blockIdx.x;
    __shared__ float s_score[N];
    __shared__ float s_mask[N];
    __shared__ float s_red[BLK / 64];
    __shared__ float s_bc;

    const int tid = threadIdx.x;
    const long long base = (long long)row * (row - 1) / 2;
    const float* mrow = mask + (size_t)row * N;

    // Pass 1: stage row into LDS, compute best_correct (max over mask==1).
    float bc = -INFINITY;
    for (int j = tid; j <= row; j += BLK) {
        float s = (j < row) ? ana_scores[base + j] : eps_scores[row];
        float m = mrow[j];
        s_score[j] = s;
        s_mask[j]  = m;
        if (m != 0.0f) bc = fmaxf(bc, s);
    }
    // Wave (64-lane) shuffle max, then cross-wave via LDS.
    for (int off = 32; off; off >>= 1) bc = fmaxf(bc, __shfl_down(bc, off));
    if ((tid & 63) == 0) s_red[tid >> 6] = bc;
    __syncthreads();
    if (tid == 0) {
        float v = s_red[0];
        for (int w = 1; w < BLK / 64; ++w) v = fmaxf(v, s_red[w]);
        s_bc = v;
    }
    __syncthreads();

    const float bcv = s_bc;
    const float lc0 = link_costs[0];      // false_link = 0.5
    const float lc1 = link_costs[1];      // wrong_link = 1.0
    const float fn  = false_new_cost[0];  // 1.5
    const float d   = s_mask[row];        // non_anaphoric indicator (diag of mask)
    const float rc  = d * lc0 + (1.0f - d) * lc1;

    // Pass 2: loss max from LDS. 0 init is exact: mask=1 entries (and the
    // zero upper triangle in the reference) contribute exactly 0.
    float loss = 0.0f;
    for (int j = tid; j <= row; j += BLK) {
        float pc = (j == row) ? fn : rc;
        float c  = (1.0f - s_mask[j]) * pc;
        loss = fmaxf(loss, c * (1.0f + s_score[j] - bcv));
    }
    for (int off = 32; off; off >>= 1) loss = fmaxf(loss, __shfl_down(loss, off));
    if ((tid & 63) == 0) s_red[tid >> 6] = loss;
    __syncthreads();
    if (tid == 0) {
        float v = s_red[0];
        for (int w = 1; w < BLK / 64; ++w) v = fmaxf(v, s_red[w]);
        out[row] = v;
    }
}

extern "C" void kernel_launch(void* const* d_in, const int* in_sizes, int n_in,
                              void* d_out, int out_size, void* d_ws, size_t ws_size,
                              hipStream_t stream) {
    const float* eps  = (const float*)d_in[0];
    const float* ana  = (const float*)d_in[1];
    const float* mask = (const float*)d_in[2];
    const float* lc   = (const float*)d_in[3];
    const float* fnc  = (const float*)d_in[4];
    float* out = (float*)d_out;

    mention_loss_kernel<<<N, BLK, 0, stream>>>(eps, ana, mask, lc, fnc, out);
}

// Round 2
// 121.122 us; speedup vs baseline: 1.0855x; 1.0855x over previous
//
#include <hip/hip_runtime.h>

#define N 4096
#define BLK 256

// Single-pass formulation. mask values are exactly 0.0 or 1.0, so each
// element j<row contributes to exactly one of two row maxes:
//   bc  = max over {m=1} of score   (global min in ref is dead code: every
//                                    row has a mask=1 entry, min <= scores)
//   sm0 = max over {m=0, j<row} of ana score
// Non-diag m=0 cost is a row-constant rc>0, so
//   loss = max(0, rc*(1+sm0-bc), (d==0)*fn*(1+eps-bc)),  d = mask[row][row]
// The 0 floor is exact: every row's m=1 entries contribute exactly 0 in the
// reference (and upper-triangle zeros likewise).
__global__ __launch_bounds__(BLK) void mention_loss_kernel(
    const float* __restrict__ eps_scores,
    const float* __restrict__ ana_scores,
    const float* __restrict__ mask,
    const float* __restrict__ link_costs,
    const float* __restrict__ false_new_cost,
    float* __restrict__ out)
{
    // Longest rows first: blockIdx 0 -> row N-1.
    const int row = N - 1 - (int)blockIdx.x;
    const int tid = threadIdx.x;
    const long long base = (long long)row * (row - 1) / 2;
    const float* __restrict__ mrow = mask + (size_t)row * (size_t)N;

    float bc  = -3.4e38f;   // max score over mask==1
    float sm0 = -3.4e38f;   // max ana score over mask==0 (j<row)

    // Fully unrolled, predicated: up to 32 loads in flight per thread.
    // Both streams are coalesced stride-4B dword loads (256 B/wave-instr).
#pragma unroll
    for (int it = 0; it < N / BLK; ++it) {
        const int j = tid + it * BLK;
        if (j < row) {
            const float s = ana_scores[base + j];
            const float m = mrow[j];
            if (m != 0.0f) bc  = fmaxf(bc,  s);
            else           sm0 = fmaxf(sm0, s);
        }
    }

    // Wave (64-lane) butterfly, then tiny cross-wave LDS reduce.
    for (int off = 32; off; off >>= 1) {
        bc  = fmaxf(bc,  __shfl_down(bc,  off));
        sm0 = fmaxf(sm0, __shfl_down(sm0, off));
    }
    __shared__ float r_bc[BLK / 64], r_sm[BLK / 64];
    if ((tid & 63) == 0) { r_bc[tid >> 6] = bc; r_sm[tid >> 6] = sm0; }
    __syncthreads();
    if (tid == 0) {
        float B = r_bc[0], S = r_sm[0];
        for (int w = 1; w < BLK / 64; ++w) {
            B = fmaxf(B, r_bc[w]);
            S = fmaxf(S, r_sm[w]);
        }
        const float e = eps_scores[row];
        const float d = mrow[row];                 // diag of solution mask
        if (d != 0.0f) B = fmaxf(B, e);            // epsilon is a correct antecedent
        const float rc = d * link_costs[0] + (1.0f - d) * link_costs[1];
        float loss = fmaxf(0.0f, rc * (1.0f + S - B));
        if (d == 0.0f) loss = fmaxf(loss, false_new_cost[0] * (1.0f + e - B));
        out[row] = loss;
    }
}

extern "C" void kernel_launch(void* const* d_in, const int* in_sizes, int n_in,
                              void* d_out, int out_size, void* d_ws, size_t ws_size,
                              hipStream_t stream) {
    const float* eps  = (const float*)d_in[0];
    const float* ana  = (const float*)d_in[1];
    const float* mask = (const float*)d_in[2];
    const float* lc   = (const float*)d_in[3];
    const float* fnc  = (const float*)d_in[4];
    float* out = (float*)d_out;

    mention_loss_kernel<<<N, BLK, 0, stream>>>(eps, ana, mask, lc, fnc, out);
}

// Round 3
// 118.828 us; speedup vs baseline: 1.1064x; 1.0193x over previous
//
#include <hip/hip_runtime.h>

#define N 4096
#define BLK 256

// 4B-aligned float4 (emits global_load_dwordx4; multi-dword loads on CDNA
// need only dword alignment).
typedef float f4u __attribute__((ext_vector_type(4), aligned(4)));
typedef float f4a __attribute__((ext_vector_type(4), aligned(16)));

// Single-pass, two running maxes per row (mask is exactly {0,1}):
//   bc  = max over {m=1} of score     (ref's global min is dead code)
//   sm0 = max over {m=0, j<row} of ana score
//   loss = max(0, rc*(1+sm0-bc), (d==0)*fn*(1+eps-bc))
__global__ __launch_bounds__(BLK) void mention_loss_kernel(
    const float* __restrict__ eps_scores,
    const float* __restrict__ ana_scores,
    const float* __restrict__ mask,
    const float* __restrict__ link_costs,
    const float* __restrict__ false_new_cost,
    float* __restrict__ out)
{
    // Longest rows first: blockIdx 0 -> row N-1.
    const int row = N - 1 - (int)blockIdx.x;
    const int tid = threadIdx.x;
    const long long base = (long long)row * (row - 1) / 2;
    const float* __restrict__ mrow = mask + (size_t)row * (size_t)N;

    float bc  = -3.4e38f;   // max score over mask==1
    float sm0 = -3.4e38f;   // max ana score over mask==0 (j<row)

    // Peel so ana_scores + base + p is 16B-aligned.
    int p = (int)((4 - (base & 3)) & 3);
    if (p > row) p = row;
    const int nvec = (row - p) >> 2;          // float4 groups in [p, p+4*nvec)
    const int t0   = p + (nvec << 2);         // tail start

    // Vectorized main: 4 elems/lane/iter, dwordx4 on both streams.
    for (int g = tid; g < nvec; g += BLK) {
        const int j = p + (g << 2);
        const f4a s4 = *(const f4a*)(ana_scores + base + j);   // 16B aligned
        const f4u m4 = *(const f4u*)(mrow + j);                // 4B aligned
        #pragma unroll
        for (int k = 0; k < 4; ++k) {
            const float s = s4[k], m = m4[k];
            if (m != 0.0f) bc  = fmaxf(bc,  s);
            else           sm0 = fmaxf(sm0, s);
        }
    }
    // Scalar peel [0,p) and tail [t0,row): <=3 elems each.
    if (tid < p) {
        const float s = ana_scores[base + tid], m = mrow[tid];
        if (m != 0.0f) bc = fmaxf(bc, s); else sm0 = fmaxf(sm0, s);
    }
    if (tid < row - t0) {
        const int j = t0 + tid;
        const float s = ana_scores[base + j], m = mrow[j];
        if (m != 0.0f) bc = fmaxf(bc, s); else sm0 = fmaxf(sm0, s);
    }

    // Wave butterfly, then cross-wave LDS reduce.
    for (int off = 32; off; off >>= 1) {
        bc  = fmaxf(bc,  __shfl_down(bc,  off));
        sm0 = fmaxf(sm0, __shfl_down(sm0, off));
    }
    __shared__ float r_bc[BLK / 64], r_sm[BLK / 64];
    if ((tid & 63) == 0) { r_bc[tid >> 6] = bc; r_sm[tid >> 6] = sm0; }
    __syncthreads();
    if (tid == 0) {
        float B = r_bc[0], S = r_sm[0];
        for (int w = 1; w < BLK / 64; ++w) {
            B = fmaxf(B, r_bc[w]);
            S = fmaxf(S, r_sm[w]);
        }
        const float e = eps_scores[row];
        const float d = mrow[row];                 // diag of solution mask
        if (d != 0.0f) B = fmaxf(B, e);            // epsilon is a correct antecedent
        const float rc = d * link_costs[0] + (1.0f - d) * link_costs[1];
        float loss = fmaxf(0.0f, rc * (1.0f + S - B));
        if (d == 0.0f) loss = fmaxf(loss, false_new_cost[0] * (1.0f + e - B));
        out[row] = loss;
    }
}

extern "C" void kernel_launch(void* const* d_in, const int* in_sizes, int n_in,
                              void* d_out, int out_size, void* d_ws, size_t ws_size,
                              hipStream_t stream) {
    const float* eps  = (const float*)d_in[0];
    const float* ana  = (const float*)d_in[1];
    const float* mask = (const float*)d_in[2];
    const float* lc   = (const float*)d_in[3];
    const float* fnc  = (const float*)d_in[4];
    float* out = (float*)d_out;

    mention_loss_kernel<<<N, BLK, 0, stream>>>(eps, ana, mask, lc, fnc, out);
}

// Round 4
// 117.835 us; speedup vs baseline: 1.1158x; 1.0084x over previous
//
#include <hip/hip_runtime.h>

#define N 4096
#define BLK 256

// 4B-aligned float4 (emits global_load_dwordx4; multi-dword loads on CDNA
// need only dword alignment).
typedef float f4u __attribute__((ext_vector_type(4), aligned(4)));
typedef float f4a __attribute__((ext_vector_type(4), aligned(16)));

// Single-pass, two running maxes per row (mask is exactly {0,1}):
//   bc  = max over {m=1} of score     (ref's global min is dead code)
//   sm0 = max over {m=0, j<row} of ana score
//   loss = max(0, rc*(1+sm0-bc), (d==0)*fn*(1+eps-bc))
__global__ __launch_bounds__(BLK) void mention_loss_kernel(
    const float* __restrict__ eps_scores,
    const float* __restrict__ ana_scores,
    const float* __restrict__ mask,
    const float* __restrict__ link_costs,
    const float* __restrict__ false_new_cost,
    float* __restrict__ out)
{
    // Longest rows first: blockIdx 0 -> row N-1.
    const int row = N - 1 - (int)blockIdx.x;
    const int tid = threadIdx.x;
    const long long base = (long long)row * (row - 1) / 2;
    const float* __restrict__ mrow = mask + (size_t)row * (size_t)N;

    float bc  = -3.4e38f;   // max score over mask==1
    float sm0 = -3.4e38f;   // max ana score over mask==0 (j<row)

    // Peel so ana_scores + base + p is 16B-aligned.
    int p = (int)((4 - (base & 3)) & 3);
    if (p > row) p = row;
    const int nvec = (row - p) >> 2;          // float4 groups in [p, p+4*nvec)
    const int t0   = p + (nvec << 2);         // tail start

    // Vectorized main: 4 elems/lane/iter, dwordx4 on both streams.
    // unroll 4 -> up to 8 independent dwordx4 in flight per thread.
#pragma unroll 4
    for (int g = tid; g < nvec; g += BLK) {
        const int j = p + (g << 2);
        const f4a s4 = *(const f4a*)(ana_scores + base + j);   // 16B aligned
        const f4u m4 = *(const f4u*)(mrow + j);                // 4B aligned
        #pragma unroll
        for (int k = 0; k < 4; ++k) {
            const float s = s4[k], m = m4[k];
            if (m != 0.0f) bc  = fmaxf(bc,  s);
            else           sm0 = fmaxf(sm0, s);
        }
    }
    // Scalar peel [0,p) and tail [t0,row): <=3 elems each.
    if (tid < p) {
        const float s = ana_scores[base + tid], m = mrow[tid];
        if (m != 0.0f) bc = fmaxf(bc, s); else sm0 = fmaxf(sm0, s);
    }
    if (tid < row - t0) {
        const int j = t0 + tid;
        const float s = ana_scores[base + j], m = mrow[j];
        if (m != 0.0f) bc = fmaxf(bc, s); else sm0 = fmaxf(sm0, s);
    }

    // Wave butterfly, then cross-wave LDS reduce.
    for (int off = 32; off; off >>= 1) {
        bc  = fmaxf(bc,  __shfl_down(bc,  off));
        sm0 = fmaxf(sm0, __shfl_down(sm0, off));
    }
    __shared__ float r_bc[BLK / 64], r_sm[BLK / 64];
    if ((tid & 63) == 0) { r_bc[tid >> 6] = bc; r_sm[tid >> 6] = sm0; }
    __syncthreads();
    if (tid == 0) {
        float B = r_bc[0], S = r_sm[0];
        for (int w = 1; w < BLK / 64; ++w) {
            B = fmaxf(B, r_bc[w]);
            S = fmaxf(S, r_sm[w]);
        }
        const float e = eps_scores[row];
        const float d = mrow[row];                 // diag of solution mask
        if (d != 0.0f) B = fmaxf(B, e);            // epsilon is a correct antecedent
        const float rc = d * link_costs[0] + (1.0f - d) * link_costs[1];
        float loss = fmaxf(0.0f, rc * (1.0f + S - B));
        if (d == 0.0f) loss = fmaxf(loss, false_new_cost[0] * (1.0f + e - B));
        out[row] = loss;
    }
}

extern "C" void kernel_launch(void* const* d_in, const int* in_sizes, int n_in,
                              void* d_out, int out_size, void* d_ws, size_t ws_size,
                              hipStream_t stream) {
    const float* eps  = (const float*)d_in[0];
    const float* ana  = (const float*)d_in[1];
    const float* mask = (const float*)d_in[2];
    const float* lc   = (const float*)d_in[3];
    const float* fnc  = (const float*)d_in[4];
    float* out = (float*)d_out;

    mention_loss_kernel<<<N, BLK, 0, stream>>>(eps, ana, mask, lc, fnc, out);
}